// Round 3
// baseline (95.801 us; speedup 1.0000x reference)
//
#include <hip/hip_runtime.h>
#include <math.h>

// DNFLayer: B=32, N=32, P0=16, P1=32, P2=16, R=3, D=8, V=2
// P = 992 perms, num_in = 112, out stride per batch = 16912.
#define NIN 112
#define NM1 31
#define OUTSTRIDE 16912
#define XSTRIDE 116   // padded x row stride: bank-start (20*jj) mod 32 distinct per jj-octet

typedef float v2f __attribute__((ext_vector_type(2)));

// Block = (b, i): 1024 blocks x 256 threads. Thread t: jj = t>>3, d = t&7.
// term(x; r) = x*s_r + t_r, (s,t) from softmax(and_kernel).
// Feature-pair packed tables: st*[g*8+d] = (s_f, s_f1, t_f, t_f1), f=2g.
// Features 0..47 (nullary+unary_i) are jj-independent -> factored into common[d][r].
__global__ __launch_bounds__(256) void dnf_main(
    const float* __restrict__ nullary, const float* __restrict__ unary,
    const float* __restrict__ binary, const float* __restrict__ andk,
    const float* __restrict__ ork, float* __restrict__ out,
    float* __restrict__ pp, unsigned int* __restrict__ cnt)
{
    __shared__ __align__(16) float4 stA[56 * 8];      // rule 0, 16B stride: conflict-free
    __shared__ __align__(16) float4 stB[56 * 8];      // rule 1
    __shared__ __align__(16) float4 stC[56 * 8];      // rule 2
    __shared__ __align__(16) float  xl[32 * XSTRIDE]; // [jj][f]
    __shared__ float okl[24];
    __shared__ float comm[24];                        // [r*8+d]: prod over f<48
    __shared__ float a0[NM1], a1[NM1], r2s[NM1];
    __shared__ float urule;
    __shared__ int amLast;

    const int t = threadIdx.x;
    const int b = blockIdx.x >> 5;
    const int i = blockIdx.x & 31;

    // --- softmax prep: 448 (g,d) records x 3 rules x 2 features ---
    for (int idx = t; idx < 56 * 8; idx += 256) {
        int g = idx >> 3, d = idx & 7;
        float sv[3][2], tv[3][2];
#pragma unroll
        for (int r = 0; r < 3; ++r)
#pragma unroll
            for (int q = 0; q < 2; ++q) {
                int base = ((r * 8 + d) * NIN + 2 * g + q) * 3;
                float w0 = andk[base], w1 = andk[base + 1], w2 = andk[base + 2];
                float m  = fmaxf(w0, fmaxf(w1, w2));
                float e0 = __expf(w0 - m), e1 = __expf(w1 - m), e2 = __expf(w2 - m);
                float inv = 1.0f / (e0 + e1 + e2);
                sv[r][q] = (e0 - e1) * inv; tv[r][q] = (e1 + e2) * inv;
            }
        stA[idx] = make_float4(sv[0][0], sv[0][1], tv[0][0], tv[0][1]);
        stB[idx] = make_float4(sv[1][0], sv[1][1], tv[1][0], tv[1][1]);
        stC[idx] = make_float4(sv[2][0], sv[2][1], tv[2][0], tv[2][1]);
    }
    if (t < 24) okl[t] = 1.0f / (1.0f + __expf(-ork[t]));

    // --- stage x[jj][0..111] = [null16 | unary_i32 | unary_j32 | bin_ij16 | bin_ji16] ---
    for (int idx = t; idx < NM1 * NIN; idx += 256) {
        int jj = idx / NIN, col = idx - jj * NIN;
        int j = jj + (jj >= i);
        float v;
        if (col < 16)      v = nullary[b * 16 + col];
        else if (col < 48) v = unary[(b * 32 + i) * 32 + (col - 16)];
        else if (col < 80) v = unary[(b * 32 + j) * 32 + (col - 48)];
        else if (col < 96) v = binary[((b * 32 + i) * 31 + jj) * 16 + (col - 80)];
        else {
            int i2 = (jj < i) ? (i - 1) : i;
            v = binary[((b * 32 + j) * 31 + i2) * 16 + (col - 96)];
        }
        xl[jj * XSTRIDE + col] = v;
    }
    __syncthreads();

    // --- common[d][r]: product over jj-independent features f<48 (pairs g=0..23) ---
    if (t < 192) {
        int cid = t >> 3;                 // 0..23 = r*8+d (wave-uniform r)
        int chunk = t & 7;
        int dd = cid & 7, rr = cid >> 3;
        const float4* tab = (rr == 0) ? stA : (rr == 1) ? stB : stC;
        v2f acc = {1.f, 1.f};
#pragma unroll
        for (int k = 0; k < 3; ++k) {
            int g = chunk * 3 + k;
            float4 A = tab[g * 8 + dd];
            v2f xx = { xl[2 * g], xl[2 * g + 1] };   // row 0 = shared features
            acc *= xx * (v2f){A.x, A.y} + (v2f){A.z, A.w};
        }
        float c = acc.x * acc.y;
#pragma unroll
        for (int m = 1; m < 8; m <<= 1) c *= __shfl_xor(c, m);
        if (chunk == 0) comm[cid] = c;
    }
    __syncthreads();

    const int jj = t >> 3;
    const int d  = t & 7;

    // --- main product: features 48..111 (pairs g=24..55) ---
    v2f acc0 = {1.f, 1.f}, acc1 = {1.f, 1.f}, acc2 = {1.f, 1.f};
    const float4* xrow4 = (const float4*)&xl[jj * XSTRIDE];  // 464B rows: 16B-aligned
    const float4* pA = &stA[d];
    const float4* pB = &stB[d];
    const float4* pC = &stC[d];
#pragma unroll 4
    for (int f4 = 12; f4 < 28; ++f4) {
        float4 xq = xrow4[f4];
#pragma unroll
        for (int h = 0; h < 2; ++h) {
            int g = 2 * f4 + h;
            v2f xx = h ? (v2f){xq.z, xq.w} : (v2f){xq.x, xq.y};
            float4 A = pA[g * 8];
            float4 Bv = pB[g * 8];
            float4 C = pC[g * 8];
            acc0 *= xx * (v2f){A.x, A.y}  + (v2f){A.z, A.w};
            acc1 *= xx * (v2f){Bv.x, Bv.y} + (v2f){Bv.z, Bv.w};
            acc2 *= xx * (v2f){C.x, C.y}  + (v2f){C.z, C.w};
        }
    }

    float c0 = acc0.x * acc0.y * comm[d];
    float c1 = acc1.x * acc1.y * comm[8 + d];
    float c2 = acc2.x * acc2.y * comm[16 + d];
    float v0 = 1.0f - c0 * okl[d];
    float v1 = 1.0f - c1 * okl[8 + d];
    float v2 = 1.0f - c2 * okl[16 + d];
#pragma unroll
    for (int m = 1; m < 8; m <<= 1) {
        v0 *= __shfl_xor(v0, m);
        v1 *= __shfl_xor(v1, m);
        v2 *= __shfl_xor(v2, m);
    }
    if (d == 0 && jj < NM1) {
        a0[jj] = v0;             // (1 - rule0) for this (b,i,jj)
        a1[jj] = v1;             // (1 - rule1)
        r2s[jj] = 1.0f - v2;     // rule2
    }
    __syncthreads();

    // --- products over jj (wave 0) + cross-block handoff ---
    if (t < 32) {
        float q0 = (t < NM1) ? a0[t] : 1.0f;
        float q1 = (t < NM1) ? a1[t] : 1.0f;
#pragma unroll
        for (int m = 1; m < 32; m <<= 1) {
            q0 *= __shfl_xor(q0, m);
            q1 *= __shfl_xor(q1, m);
        }
        if (t == 0) {
            atomicExch(&pp[b * 32 + i], q0);     // coherent-point store
            __threadfence();                     // order exch before cnt add
            unsigned old = atomicAdd(&cnt[b], 1u);
            amLast = (old == 31u) ? 1 : 0;
            urule = 1.0f - q1;
        }
    }
    __syncthreads();

    // --- unary output: 32 channels, channel 31 merged ---
    if (t < 32) {
        float old = xl[16 + t];
        float val = (t == 31) ? 1.0f - (1.0f - old) * (1.0f - urule) : old;
        out[b * OUTSTRIDE + 16 + i * 32 + t] = val;
    }
    // --- binary output: 31*16 values, channel 15 merged with rule2 ---
    for (int idx = t; idx < NM1 * 16; idx += 256) {
        int jj2 = idx >> 4, c = idx & 15;
        float old = xl[jj2 * XSTRIDE + 80 + c];
        float val = old;
        if (c == 15) val = 1.0f - (1.0f - old) * (1.0f - r2s[jj2]);
        out[b * OUTSTRIDE + 16 + 1024 + (i * 31 + jj2) * 16 + c] = val;
    }

    // --- last block for batch b: nullary probsum over all i + nullary output ---
    if (amLast && t < 32) {
        float ps = atomicAdd(&pp[b * 32 + t], 0.0f);   // coherent-point read
#pragma unroll
        for (int m = 1; m < 32; m <<= 1) ps *= __shfl_xor(ps, m);
        if (t < 16) {
            float old = nullary[b * 16 + t];
            // merged = 1 - (1-old)*rule0comp, rule0 = 1 - ps => 1 - (1-old)*ps
            out[b * OUTSTRIDE + t] = (t == 15) ? 1.0f - (1.0f - old) * ps : old;
        }
    }
}

extern "C" void kernel_launch(void* const* d_in, const int* in_sizes, int n_in,
                              void* d_out, int out_size, void* d_ws, size_t ws_size,
                              hipStream_t stream) {
    const float* nullary = (const float*)d_in[0];
    const float* unary   = (const float*)d_in[1];
    const float* binary  = (const float*)d_in[2];
    const float* andk    = (const float*)d_in[3];
    const float* ork     = (const float*)d_in[4];
    float* out = (float*)d_out;
    float* pp = (float*)d_ws;                              // 1024 floats
    unsigned int* cnt = (unsigned int*)((char*)d_ws + 4096); // 32 u32 counters

    hipMemsetAsync(cnt, 0, 128, stream);                   // graph-capturable memset node
    dnf_main<<<dim3(1024), dim3(256), 0, stream>>>(nullary, unary, binary, andk, ork, out, pp, cnt);
}

// Round 4
// 79.625 us; speedup vs baseline: 1.2032x; 1.2032x over previous
//
#include <hip/hip_runtime.h>
#include <math.h>

// DNFLayer: B=32, N=32, P0=16, P1=32, P2=16, R=3, D=8, V=2
// P = 992 perms, num_in = 112, out stride per batch = 16912.
#define NIN 112
#define NM1 31
#define OUTSTRIDE 16912
#define XSTRIDE 116   // padded x row stride: bank-start (20*jj) mod 32 distinct per jj-octet

typedef float v2f __attribute__((ext_vector_type(2)));

// Block = (b, i): 1024 blocks x 256 threads. Thread t: jj = t>>3, d = t&7.
// term(x; r) = x*s_r + t_r, (s,t) from softmax(and_kernel).
// Feature-pair packed tables: st*[g*8+d] = (s_f, s_f1, t_f, t_f1), f=2g.
// Features 0..47 (nullary+unary_i) are jj-independent -> factored into comm[r*8+d].
// NO cross-block atomics/fences (R3 lesson: device-scope fence x1024 blocks cost +14us).
__global__ __launch_bounds__(256) void dnf_main(
    const float* __restrict__ nullary, const float* __restrict__ unary,
    const float* __restrict__ binary, const float* __restrict__ andk,
    const float* __restrict__ ork, float* __restrict__ out,
    float* __restrict__ pp)
{
    __shared__ __align__(16) float4 stA[56 * 8];      // rule 0: 16B stride, bank 4d, broadcast per d -> conflict-free
    __shared__ __align__(16) float4 stB[56 * 8];      // rule 1
    __shared__ __align__(16) float4 stC[56 * 8];      // rule 2
    __shared__ __align__(16) float  xl[32 * XSTRIDE]; // [jj][f]
    __shared__ float okl[24];
    __shared__ float comm[24];                        // [r*8+d]: prod over features f<48
    __shared__ float a0[NM1], a1[NM1], r2s[NM1];
    __shared__ float urule;

    const int t = threadIdx.x;
    const int b = blockIdx.x >> 5;
    const int i = blockIdx.x & 31;

    // --- softmax prep: 448 (g,d) records x 3 rules x 2 features ---
    for (int idx = t; idx < 56 * 8; idx += 256) {
        int g = idx >> 3, d = idx & 7;
        float sv[3][2], tv[3][2];
#pragma unroll
        for (int r = 0; r < 3; ++r)
#pragma unroll
            for (int q = 0; q < 2; ++q) {
                int base = ((r * 8 + d) * NIN + 2 * g + q) * 3;
                float w0 = andk[base], w1 = andk[base + 1], w2 = andk[base + 2];
                float m  = fmaxf(w0, fmaxf(w1, w2));
                float e0 = __expf(w0 - m), e1 = __expf(w1 - m), e2 = __expf(w2 - m);
                float inv = 1.0f / (e0 + e1 + e2);
                sv[r][q] = (e0 - e1) * inv; tv[r][q] = (e1 + e2) * inv;
            }
        stA[idx] = make_float4(sv[0][0], sv[0][1], tv[0][0], tv[0][1]);
        stB[idx] = make_float4(sv[1][0], sv[1][1], tv[1][0], tv[1][1]);
        stC[idx] = make_float4(sv[2][0], sv[2][1], tv[2][0], tv[2][1]);
    }
    if (t < 24) okl[t] = 1.0f / (1.0f + __expf(-ork[t]));

    // --- stage x[jj][0..111] = [null16 | unary_i32 | unary_j32 | bin_ij16 | bin_ji16] ---
    for (int idx = t; idx < NM1 * NIN; idx += 256) {
        int jj = idx / NIN, col = idx - jj * NIN;
        int j = jj + (jj >= i);
        float v;
        if (col < 16)      v = nullary[b * 16 + col];
        else if (col < 48) v = unary[(b * 32 + i) * 32 + (col - 16)];
        else if (col < 80) v = unary[(b * 32 + j) * 32 + (col - 48)];
        else if (col < 96) v = binary[((b * 32 + i) * 31 + jj) * 16 + (col - 80)];
        else {
            int i2 = (jj < i) ? (i - 1) : i;
            v = binary[((b * 32 + j) * 31 + i2) * 16 + (col - 96)];
        }
        xl[jj * XSTRIDE + col] = v;
    }
    __syncthreads();

    // --- comm[r*8+d]: product over jj-independent features f<48 (pairs g=0..23) ---
    if (t < 192) {
        int cid = t >> 3;                 // 0..23 = r*8+d
        int chunk = t & 7;
        int dd = cid & 7, rr = cid >> 3;
        const float4* tab = (rr == 0) ? stA : (rr == 1) ? stB : stC;
        v2f acc = {1.f, 1.f};
#pragma unroll
        for (int k = 0; k < 3; ++k) {
            int g = chunk * 3 + k;
            float4 A = tab[g * 8 + dd];
            v2f xx = { xl[2 * g], xl[2 * g + 1] };   // row 0 = shared features
            acc *= xx * (v2f){A.x, A.y} + (v2f){A.z, A.w};
        }
        float c = acc.x * acc.y;
#pragma unroll
        for (int m = 1; m < 8; m <<= 1) c *= __shfl_xor(c, m);
        if (chunk == 0) comm[cid] = c;
    }
    __syncthreads();

    const int jj = t >> 3;
    const int d  = t & 7;

    // --- main product: per-jj features 48..111 (pairs g=24..55) ---
    v2f acc0 = {1.f, 1.f}, acc1 = {1.f, 1.f}, acc2 = {1.f, 1.f};
    const float4* xrow4 = (const float4*)&xl[jj * XSTRIDE];  // 464B rows: 16B-aligned
    const float4* pA = &stA[d];
    const float4* pB = &stB[d];
    const float4* pC = &stC[d];
#pragma unroll 4
    for (int f4 = 12; f4 < 28; ++f4) {
        float4 xq = xrow4[f4];
#pragma unroll
        for (int h = 0; h < 2; ++h) {
            int g = 2 * f4 + h;
            v2f xx = h ? (v2f){xq.z, xq.w} : (v2f){xq.x, xq.y};
            float4 A  = pA[g * 8];
            float4 Bv = pB[g * 8];
            float4 C  = pC[g * 8];
            acc0 *= xx * (v2f){A.x,  A.y}  + (v2f){A.z,  A.w};
            acc1 *= xx * (v2f){Bv.x, Bv.y} + (v2f){Bv.z, Bv.w};
            acc2 *= xx * (v2f){C.x,  C.y}  + (v2f){C.z,  C.w};
        }
    }

    float c0 = acc0.x * acc0.y * comm[d];
    float c1 = acc1.x * acc1.y * comm[8 + d];
    float c2 = acc2.x * acc2.y * comm[16 + d];
    float v0 = 1.0f - c0 * okl[d];
    float v1 = 1.0f - c1 * okl[8 + d];
    float v2 = 1.0f - c2 * okl[16 + d];
#pragma unroll
    for (int m = 1; m < 8; m <<= 1) {
        v0 *= __shfl_xor(v0, m);
        v1 *= __shfl_xor(v1, m);
        v2 *= __shfl_xor(v2, m);
    }
    if (d == 0 && jj < NM1) {
        a0[jj] = v0;             // (1 - rule0) for this (b,i,jj)
        a1[jj] = v1;             // (1 - rule1)
        r2s[jj] = 1.0f - v2;     // rule2
    }
    __syncthreads();

    // --- products over jj (wave 0, shuffle reduce) ---
    if (t < 32) {
        float q0 = (t < NM1) ? a0[t] : 1.0f;
        float q1 = (t < NM1) ? a1[t] : 1.0f;
#pragma unroll
        for (int m = 1; m < 32; m <<= 1) {
            q0 *= __shfl_xor(q0, m);
            q1 *= __shfl_xor(q1, m);
        }
        if (t == 0) {
            pp[b * 32 + i] = q0;     // partial nullary product for (b,i)
            urule = 1.0f - q1;       // unary rule for (b,i)
        }
    }
    __syncthreads();

    // --- unary output: 32 channels, channel 31 merged ---
    if (t < 32) {
        float old = xl[16 + t];
        float val = (t == 31) ? 1.0f - (1.0f - old) * (1.0f - urule) : old;
        out[b * OUTSTRIDE + 16 + i * 32 + t] = val;
    }
    // --- binary output: 31*16 values, channel 15 merged with rule2 ---
    for (int idx = t; idx < NM1 * 16; idx += 256) {
        int jj2 = idx >> 4, c = idx & 15;
        float old = xl[jj2 * XSTRIDE + 80 + c];
        float val = old;
        if (c == 15) val = 1.0f - (1.0f - old) * (1.0f - r2s[jj2]);
        out[b * OUTSTRIDE + 16 + 1024 + (i * 31 + jj2) * 16 + c] = val;
    }
}

// Finalize: nullary probsum across all i per batch + nullary output (16 channels).
__global__ __launch_bounds__(1024) void dnf_final(
    const float* __restrict__ nullary, const float* __restrict__ pp,
    float* __restrict__ out)
{
    int t = threadIdx.x;
    int b = t >> 5, s = t & 31;
    float v = pp[b * 32 + s];
#pragma unroll
    for (int m = 1; m < 32; m <<= 1) v *= __shfl_xor(v, m);  // masks <32 stay in 32-lane half
    if (s < 16) {
        float old = nullary[b * 16 + s];
        // merged = 1 - (1-old)*(1-rule0), rule0 = 1 - v  =>  1 - (1-old)*v
        float val = (s == 15) ? 1.0f - (1.0f - old) * v : old;
        out[b * OUTSTRIDE + s] = val;
    }
}

extern "C" void kernel_launch(void* const* d_in, const int* in_sizes, int n_in,
                              void* d_out, int out_size, void* d_ws, size_t ws_size,
                              hipStream_t stream) {
    const float* nullary = (const float*)d_in[0];
    const float* unary   = (const float*)d_in[1];
    const float* binary  = (const float*)d_in[2];
    const float* andk    = (const float*)d_in[3];
    const float* ork     = (const float*)d_in[4];
    float* out = (float*)d_out;
    float* pp  = (float*)d_ws;   // 1024 floats of scratch

    dnf_main<<<dim3(1024), dim3(256), 0, stream>>>(nullary, unary, binary, andk, ork, out, pp);
    dnf_final<<<dim3(1), dim3(1024), 0, stream>>>(nullary, pp, out);
}

// Round 5
// 73.528 us; speedup vs baseline: 1.3029x; 1.0829x over previous
//
#include <hip/hip_runtime.h>
#include <math.h>

// DNFLayer: B=32, N=32, P0=16, P1=32, P2=16, R=3, D=8, V=2
// P = 992 perms, num_in = 112, out stride per batch = 16912.
#define NM1 31
#define OUTSTRIDE 16912

typedef float v2f __attribute__((ext_vector_type(2)));

// Block = (b, i-pair): 512 blocks x 256 threads. Thread t: jj = t>>3, d = t&7.
// Each thread computes conjunct products for (i0,jj,d) AND (i1,jj,d), sharing
// every st-table LDS read between the two (st is jj- and i-independent).
// x features 48..111 live in registers (direct global loads, VMEM pipe);
// only the st tables + tiny comm/reduction arrays use LDS.
__global__ __launch_bounds__(256) void dnf_main(
    const float* __restrict__ nullary, const float* __restrict__ unary,
    const float* __restrict__ binary, const float* __restrict__ andk,
    const float* __restrict__ ork, float* __restrict__ out,
    float* __restrict__ pp)
{
    __shared__ __align__(16) float4 stA[56 * 8];   // rule 0: (s_f,s_f1,t_f,t_f1), f=2g
    __shared__ __align__(16) float4 stB[56 * 8];   // rule 1
    __shared__ __align__(16) float4 stC[56 * 8];   // rule 2
    __shared__ __align__(16) float  xsh[80];       // [null16 | unary_i0 32 | unary_i1 32]
    __shared__ float okl[24];
    __shared__ float comm[2][24];                  // [i][r*8+d]: prod over features f<48
    __shared__ float a0s[2][NM1], a1s[2][NM1];

    const int t  = threadIdx.x;
    const int b  = blockIdx.x >> 4;
    const int ip = blockIdx.x & 15;
    const int i0 = ip * 2, i1 = ip * 2 + 1;

    const int jj  = t >> 3;
    const int d   = t & 7;
    const int jjc = (jj < NM1) ? jj : NM1 - 1;   // lane jj==31 computes garbage, never stored

    // ---- early x loads: features 48..111 for i0 and i1 (16 float4 each) ----
    float4 xr0[16], xr1[16];
    {
        int j0 = jjc + (jjc >= i0);
        const float4* uj  = (const float4*)&unary[(b * 32 + j0) * 32];
#pragma unroll
        for (int q = 0; q < 8; ++q) xr0[q] = uj[q];
        const float4* bij = (const float4*)&binary[((b * 32 + i0) * 31 + jjc) * 16];
#pragma unroll
        for (int q = 0; q < 4; ++q) xr0[8 + q] = bij[q];
        int i2 = (jjc < i0) ? i0 - 1 : i0;
        const float4* bji = (const float4*)&binary[((b * 32 + j0) * 31 + i2) * 16];
#pragma unroll
        for (int q = 0; q < 4; ++q) xr0[12 + q] = bji[q];
    }
    {
        int j1 = jjc + (jjc >= i1);
        const float4* uj  = (const float4*)&unary[(b * 32 + j1) * 32];
#pragma unroll
        for (int q = 0; q < 8; ++q) xr1[q] = uj[q];
        const float4* bij = (const float4*)&binary[((b * 32 + i1) * 31 + jjc) * 16];
#pragma unroll
        for (int q = 0; q < 4; ++q) xr1[8 + q] = bij[q];
        int i2 = (jjc < i1) ? i1 - 1 : i1;
        const float4* bji = (const float4*)&binary[((b * 32 + j1) * 31 + i2) * 16];
#pragma unroll
        for (int q = 0; q < 4; ++q) xr1[12 + q] = bji[q];
    }

    // ---- softmax prep: 448 (g,d) records x 3 rules x 2 features ----
    for (int idx = t; idx < 56 * 8; idx += 256) {
        int g = idx >> 3, dd = idx & 7;
        float sv[3][2], tv[3][2];
#pragma unroll
        for (int r = 0; r < 3; ++r)
#pragma unroll
            for (int q = 0; q < 2; ++q) {
                int base = ((r * 8 + dd) * 112 + 2 * g + q) * 3;
                float w0 = andk[base], w1 = andk[base + 1], w2 = andk[base + 2];
                float m  = fmaxf(w0, fmaxf(w1, w2));
                float e0 = __expf(w0 - m), e1 = __expf(w1 - m), e2 = __expf(w2 - m);
                float inv = 1.0f / (e0 + e1 + e2);
                sv[r][q] = (e0 - e1) * inv; tv[r][q] = (e1 + e2) * inv;
            }
        stA[idx] = make_float4(sv[0][0], sv[0][1], tv[0][0], tv[0][1]);
        stB[idx] = make_float4(sv[1][0], sv[1][1], tv[1][0], tv[1][1]);
        stC[idx] = make_float4(sv[2][0], sv[2][1], tv[2][0], tv[2][1]);
    }
    if (t < 24) okl[t] = 1.0f / (1.0f + __expf(-ork[t]));
    if (t < 20) {
        float4 v = (t < 4)  ? ((const float4*)&nullary[b * 16])[t]
                 : (t < 12) ? ((const float4*)&unary[(b * 32 + i0) * 32])[t - 4]
                            : ((const float4*)&unary[(b * 32 + i1) * 32])[t - 12];
        ((float4*)xsh)[t] = v;
    }
    __syncthreads();

    // ---- comm[i][r*8+d]: product over jj-independent features f<48 (pairs g=0..23) ----
    if (t < 192) {
        int cid = t >> 3, chunk = t & 7;
        int dd = cid & 7, rr = cid >> 3;
        const float4* tab = (rr == 0) ? stA : (rr == 1) ? stB : stC;
#pragma unroll
        for (int ii = 0; ii < 2; ++ii) {
            v2f acc = {1.f, 1.f};
#pragma unroll
            for (int k = 0; k < 3; ++k) {
                int g = chunk * 3 + k, f = 2 * g;
                float xa = (f < 16) ? xsh[f]     : xsh[16 + 32 * ii + f - 16];
                float xb = (f < 15) ? xsh[f + 1] : xsh[16 + 32 * ii + f + 1 - 16];
                float4 A = tab[g * 8 + dd];
                v2f xx = {xa, xb};
                acc *= xx * (v2f){A.x, A.y} + (v2f){A.z, A.w};
            }
            float c = acc.x * acc.y;
#pragma unroll
            for (int m = 1; m < 8; m <<= 1) c *= __shfl_xor(c, m);
            if (chunk == 0) comm[ii][cid] = c;
        }
    }
    __syncthreads();

    // ---- main product: features 48..111 (pairs g=24..55), both i's per st read ----
    v2f p00 = {1.f,1.f}, p10 = {1.f,1.f}, p20 = {1.f,1.f};
    v2f p01 = {1.f,1.f}, p11 = {1.f,1.f}, p21 = {1.f,1.f};
    const float4* pA = &stA[d];
    const float4* pB = &stB[d];
    const float4* pC = &stC[d];
#pragma unroll
    for (int g = 24; g < 56; ++g) {
        int h = (g - 24) >> 1;                    // compile-time after unroll
        float4 A = pA[g * 8], Bv = pB[g * 8], C = pC[g * 8];
        v2f x0 = (g & 1) ? (v2f){xr0[h].z, xr0[h].w} : (v2f){xr0[h].x, xr0[h].y};
        v2f x1 = (g & 1) ? (v2f){xr1[h].z, xr1[h].w} : (v2f){xr1[h].x, xr1[h].y};
        v2f sA = {A.x, A.y},  tA = {A.z, A.w};
        v2f sB = {Bv.x, Bv.y}, tB = {Bv.z, Bv.w};
        v2f sC = {C.x, C.y},  tC = {C.z, C.w};
        p00 *= x0 * sA + tA;  p10 *= x0 * sB + tB;  p20 *= x0 * sC + tC;
        p01 *= x1 * sA + tA;  p11 *= x1 * sB + tB;  p21 *= x1 * sC + tC;
    }

    float v00 = 1.0f - (p00.x * p00.y * comm[0][d])      * okl[d];
    float v10 = 1.0f - (p10.x * p10.y * comm[0][8 + d])  * okl[8 + d];
    float v20 = 1.0f - (p20.x * p20.y * comm[0][16 + d]) * okl[16 + d];
    float v01 = 1.0f - (p01.x * p01.y * comm[1][d])      * okl[d];
    float v11 = 1.0f - (p11.x * p11.y * comm[1][8 + d])  * okl[8 + d];
    float v21 = 1.0f - (p21.x * p21.y * comm[1][16 + d]) * okl[16 + d];
#pragma unroll
    for (int m = 1; m < 8; m <<= 1) {
        v00 *= __shfl_xor(v00, m); v10 *= __shfl_xor(v10, m); v20 *= __shfl_xor(v20, m);
        v01 *= __shfl_xor(v01, m); v11 *= __shfl_xor(v11, m); v21 *= __shfl_xor(v21, m);
    }

    if (d == 0 && jj < NM1) {
        a0s[0][jj] = v00;  a1s[0][jj] = v10;
        a0s[1][jj] = v01;  a1s[1][jj] = v11;

        // binary outputs straight from registers; c==15 merged with local rule2 = 1-v2
        float r20 = 1.0f - v20;
        xr0[11].w = 1.0f - (1.0f - xr0[11].w) * (1.0f - r20);
        float4* ob0 = (float4*)&out[b * OUTSTRIDE + 1040 + (i0 * 31 + jj) * 16];
#pragma unroll
        for (int q = 0; q < 4; ++q) ob0[q] = xr0[8 + q];

        float r21 = 1.0f - v21;
        xr1[11].w = 1.0f - (1.0f - xr1[11].w) * (1.0f - r21);
        float4* ob1 = (float4*)&out[b * OUTSTRIDE + 1040 + (i1 * 31 + jj) * 16];
#pragma unroll
        for (int q = 0; q < 4; ++q) ob1[q] = xr1[8 + q];
    }
    __syncthreads();

    // ---- per-i reductions over jj + unary/nullary-partial outputs ----
    if (t < 32) {                                  // wave 0 -> i0
        float q0 = (t < NM1) ? a0s[0][t] : 1.0f;
        float q1 = (t < NM1) ? a1s[0][t] : 1.0f;
#pragma unroll
        for (int m = 1; m < 32; m <<= 1) { q0 *= __shfl_xor(q0, m); q1 *= __shfl_xor(q1, m); }
        if (t == 0) pp[b * 32 + i0] = q0;
        float old = xsh[16 + t];                   // unary_i0 row
        float val = (t == 31) ? 1.0f - (1.0f - old) * q1 : old;  // 1-(1-old)*(1-urule), urule=1-q1
        out[b * OUTSTRIDE + 16 + i0 * 32 + t] = val;
    } else if (t >= 64 && t < 96) {                // wave 1 -> i1
        int s = t - 64;
        float q0 = (s < NM1) ? a0s[1][s] : 1.0f;
        float q1 = (s < NM1) ? a1s[1][s] : 1.0f;
#pragma unroll
        for (int m = 1; m < 32; m <<= 1) { q0 *= __shfl_xor(q0, m); q1 *= __shfl_xor(q1, m); }
        if (s == 0) pp[b * 32 + i1] = q0;
        float old = xsh[48 + s];                   // unary_i1 row
        float val = (s == 31) ? 1.0f - (1.0f - old) * q1 : old;
        out[b * OUTSTRIDE + 16 + i1 * 32 + s] = val;
    }
}

// Finalize: nullary probsum across all i per batch + nullary output (16 channels).
__global__ __launch_bounds__(1024) void dnf_final(
    const float* __restrict__ nullary, const float* __restrict__ pp,
    float* __restrict__ out)
{
    int t = threadIdx.x;
    int b = t >> 5, s = t & 31;
    float v = pp[b * 32 + s];
#pragma unroll
    for (int m = 1; m < 32; m <<= 1) v *= __shfl_xor(v, m);
    if (s < 16) {
        float old = nullary[b * 16 + s];
        // merged = 1 - (1-old)*(1-rule0), rule0 = 1 - v  =>  1 - (1-old)*v
        float val = (s == 15) ? 1.0f - (1.0f - old) * v : old;
        out[b * OUTSTRIDE + s] = val;
    }
}

extern "C" void kernel_launch(void* const* d_in, const int* in_sizes, int n_in,
                              void* d_out, int out_size, void* d_ws, size_t ws_size,
                              hipStream_t stream) {
    const float* nullary = (const float*)d_in[0];
    const float* unary   = (const float*)d_in[1];
    const float* binary  = (const float*)d_in[2];
    const float* andk    = (const float*)d_in[3];
    const float* ork     = (const float*)d_in[4];
    float* out = (float*)d_out;
    float* pp  = (float*)d_ws;   // 1024 floats of scratch

    dnf_main<<<dim3(512), dim3(256), 0, stream>>>(nullary, unary, binary, andk, ork, out, pp);
    dnf_final<<<dim3(1), dim3(1024), 0, stream>>>(nullary, pp, out);
}

// Round 6
// 73.020 us; speedup vs baseline: 1.3120x; 1.0070x over previous
//
#include <hip/hip_runtime.h>
#include <math.h>

// DNFLayer: B=32, N=32, P0=16, P1=32, P2=16, R=3, D=8, V=2
// P = 992 perms, num_in = 112, out stride per batch = 16912.
#define NM1 31
#define OUTSTRIDE 16912

typedef float v2f __attribute__((ext_vector_type(2)));

// Block = (b, i-quad): 256 blocks x 512 threads. half = t>>8 picks the i-pair;
// within a half: jj = th>>3, d = th&7. Each thread computes conjunct products
// for its half's (i0,jj,d) and (i1,jj,d), sharing every st-table LDS read.
// x features 48..111 live in registers (direct global loads, VMEM pipe).
// Softmax prep: 448 records / 512 threads = 1 iter (halved vs R5), no-max exp
// (and_kernel ~ N(2,1): fp32-safe).
__global__ __launch_bounds__(512) void dnf_main(
    const float* __restrict__ nullary, const float* __restrict__ unary,
    const float* __restrict__ binary, const float* __restrict__ andk,
    const float* __restrict__ ork, float* __restrict__ out,
    float* __restrict__ pp)
{
    __shared__ __align__(16) float4 stA[56 * 8];   // rule 0: (s_f,s_f1,t_f,t_f1), f=2g
    __shared__ __align__(16) float4 stB[56 * 8];   // rule 1
    __shared__ __align__(16) float4 stC[56 * 8];   // rule 2
    __shared__ __align__(16) float  xsh[16 + 4 * 32];  // [null16 | unary rows i0..i3]
    __shared__ float okl[24];
    __shared__ float comm[4][24];                  // [i_local][r*8+d]: prod over f<48
    __shared__ float a0s[4][NM1], a1s[4][NM1];

    const int t    = threadIdx.x;
    const int b    = blockIdx.x >> 3;
    const int ip   = blockIdx.x & 7;
    const int half = t >> 8;
    const int th   = t & 255;
    const int jj   = th >> 3;
    const int d    = th & 7;
    const int jjc  = (jj < NM1) ? jj : NM1 - 1;    // lane jj==31 computes garbage, never stored
    const int li0  = half * 2, li1 = half * 2 + 1; // local i indices
    const int i0   = ip * 4 + li0, i1 = ip * 4 + li1;

    // ---- early x loads: features 48..111 for i0 and i1 (16 float4 each) ----
    float4 xr0[16], xr1[16];
    {
        int j0 = jjc + (jjc >= i0);
        const float4* uj  = (const float4*)&unary[(b * 32 + j0) * 32];
#pragma unroll
        for (int q = 0; q < 8; ++q) xr0[q] = uj[q];
        const float4* bij = (const float4*)&binary[((b * 32 + i0) * 31 + jjc) * 16];
#pragma unroll
        for (int q = 0; q < 4; ++q) xr0[8 + q] = bij[q];
        int i2 = (jjc < i0) ? i0 - 1 : i0;
        const float4* bji = (const float4*)&binary[((b * 32 + j0) * 31 + i2) * 16];
#pragma unroll
        for (int q = 0; q < 4; ++q) xr0[12 + q] = bji[q];
    }
    {
        int j1 = jjc + (jjc >= i1);
        const float4* uj  = (const float4*)&unary[(b * 32 + j1) * 32];
#pragma unroll
        for (int q = 0; q < 8; ++q) xr1[q] = uj[q];
        const float4* bij = (const float4*)&binary[((b * 32 + i1) * 31 + jjc) * 16];
#pragma unroll
        for (int q = 0; q < 4; ++q) xr1[8 + q] = bij[q];
        int i2 = (jjc < i1) ? i1 - 1 : i1;
        const float4* bji = (const float4*)&binary[((b * 32 + j1) * 31 + i2) * 16];
#pragma unroll
        for (int q = 0; q < 4; ++q) xr1[12 + q] = bji[q];
    }

    // ---- softmax prep: 448 (g,dd) records, 1 iter/thread, no-max exp ----
    if (t < 448) {
        int g = t >> 3, dd = t & 7;
        float sv[3][2], tv[3][2];
#pragma unroll
        for (int r = 0; r < 3; ++r) {
            const float2* w = (const float2*)&andk[((r * 8 + dd) * 112 + 2 * g) * 3];
            float2 f01 = w[0], f23 = w[1], f45 = w[2];
            {   // q = 0: w0=f01.x w1=f01.y w2=f23.x
                float e0 = __expf(f01.x), e1 = __expf(f01.y), e2 = __expf(f23.x);
                float inv = 1.0f / (e0 + e1 + e2);
                sv[r][0] = (e0 - e1) * inv; tv[r][0] = (e1 + e2) * inv;
            }
            {   // q = 1: w0=f23.y w1=f45.x w2=f45.y
                float e0 = __expf(f23.y), e1 = __expf(f45.x), e2 = __expf(f45.y);
                float inv = 1.0f / (e0 + e1 + e2);
                sv[r][1] = (e0 - e1) * inv; tv[r][1] = (e1 + e2) * inv;
            }
        }
        int idx = g * 8 + dd;
        stA[idx] = make_float4(sv[0][0], sv[0][1], tv[0][0], tv[0][1]);
        stB[idx] = make_float4(sv[1][0], sv[1][1], tv[1][0], tv[1][1]);
        stC[idx] = make_float4(sv[2][0], sv[2][1], tv[2][0], tv[2][1]);
    }
    if (t >= 448 && t < 472) okl[t - 448] = 1.0f / (1.0f + __expf(-ork[t - 448]));
    if (t >= 472 && t < 508) {
        int k = t - 472;   // 0..35: 4 nullary float4 + 32 unary-row float4
        float4 v;
        if (k < 4) v = ((const float4*)&nullary[b * 16])[k];
        else {
            int il = (k - 4) >> 3, chunk = (k - 4) & 7;
            v = ((const float4*)&unary[(b * 32 + ip * 4 + il) * 32])[chunk];
        }
        ((float4*)xsh)[k] = v;
    }
    __syncthreads();

    // ---- comm[il][r*8+d]: product over jj-independent features f<48 (pairs g=0..23) ----
    if (t < 192) {
        int cid = t >> 3, chunk = t & 7;
        int dd = cid & 7, rr = cid >> 3;
        const float4* tab = (rr == 0) ? stA : (rr == 1) ? stB : stC;
#pragma unroll
        for (int il = 0; il < 4; ++il) {
            v2f acc = {1.f, 1.f};
#pragma unroll
            for (int k = 0; k < 3; ++k) {
                int g = chunk * 3 + k, f = 2 * g;
                float xa = (f < 16) ? xsh[f]     : xsh[16 + 32 * il + f - 16];
                float xb = (f < 15) ? xsh[f + 1] : xsh[16 + 32 * il + f + 1 - 16];
                float4 A = tab[g * 8 + dd];
                v2f xx = {xa, xb};
                acc *= xx * (v2f){A.x, A.y} + (v2f){A.z, A.w};
            }
            float c = acc.x * acc.y;
#pragma unroll
            for (int m = 1; m < 8; m <<= 1) c *= __shfl_xor(c, m);
            if (chunk == 0) comm[il][cid] = c;
        }
    }
    __syncthreads();

    // ---- main product: features 48..111 (pairs g=24..55), both i's per st read ----
    v2f p00 = {1.f,1.f}, p10 = {1.f,1.f}, p20 = {1.f,1.f};
    v2f p01 = {1.f,1.f}, p11 = {1.f,1.f}, p21 = {1.f,1.f};
    const float4* pA = &stA[d];
    const float4* pB = &stB[d];
    const float4* pC = &stC[d];
#pragma unroll
    for (int g = 24; g < 56; ++g) {
        int h = (g - 24) >> 1;                    // compile-time after unroll
        float4 A = pA[g * 8], Bv = pB[g * 8], C = pC[g * 8];
        v2f x0 = (g & 1) ? (v2f){xr0[h].z, xr0[h].w} : (v2f){xr0[h].x, xr0[h].y};
        v2f x1 = (g & 1) ? (v2f){xr1[h].z, xr1[h].w} : (v2f){xr1[h].x, xr1[h].y};
        v2f sA = {A.x, A.y},  tA = {A.z, A.w};
        v2f sB = {Bv.x, Bv.y}, tB = {Bv.z, Bv.w};
        v2f sC = {C.x, C.y},  tC = {C.z, C.w};
        p00 *= x0 * sA + tA;  p10 *= x0 * sB + tB;  p20 *= x0 * sC + tC;
        p01 *= x1 * sA + tA;  p11 *= x1 * sB + tB;  p21 *= x1 * sC + tC;
    }

    float v00 = 1.0f - (p00.x * p00.y * comm[li0][d])      * okl[d];
    float v10 = 1.0f - (p10.x * p10.y * comm[li0][8 + d])  * okl[8 + d];
    float v20 = 1.0f - (p20.x * p20.y * comm[li0][16 + d]) * okl[16 + d];
    float v01 = 1.0f - (p01.x * p01.y * comm[li1][d])      * okl[d];
    float v11 = 1.0f - (p11.x * p11.y * comm[li1][8 + d])  * okl[8 + d];
    float v21 = 1.0f - (p21.x * p21.y * comm[li1][16 + d]) * okl[16 + d];
#pragma unroll
    for (int m = 1; m < 8; m <<= 1) {
        v00 *= __shfl_xor(v00, m); v10 *= __shfl_xor(v10, m); v20 *= __shfl_xor(v20, m);
        v01 *= __shfl_xor(v01, m); v11 *= __shfl_xor(v11, m); v21 *= __shfl_xor(v21, m);
    }

    if (d == 0 && jj < NM1) {
        a0s[li0][jj] = v00;  a1s[li0][jj] = v10;
        a0s[li1][jj] = v01;  a1s[li1][jj] = v11;

        // binary outputs straight from registers; c==15 merged with local rule2 = 1-v2
        xr0[11].w = 1.0f - (1.0f - xr0[11].w) * v20;   // 1-(1-old)*(1-r2), r2=1-v20
        float4* ob0 = (float4*)&out[b * OUTSTRIDE + 1040 + (i0 * 31 + jj) * 16];
#pragma unroll
        for (int q = 0; q < 4; ++q) ob0[q] = xr0[8 + q];

        xr1[11].w = 1.0f - (1.0f - xr1[11].w) * v21;
        float4* ob1 = (float4*)&out[b * OUTSTRIDE + 1040 + (i1 * 31 + jj) * 16];
#pragma unroll
        for (int q = 0; q < 4; ++q) ob1[q] = xr1[8 + q];
    }
    __syncthreads();

    // ---- per-i reductions over jj + unary outputs: wave w (0..3) handles local i=w ----
    if (t < 256) {
        int w = t >> 6, s = t & 63;
        if (s < 32) {
            float q0 = (s < NM1) ? a0s[w][s] : 1.0f;
            float q1 = (s < NM1) ? a1s[w][s] : 1.0f;
#pragma unroll
            for (int m = 1; m < 32; m <<= 1) { q0 *= __shfl_xor(q0, m); q1 *= __shfl_xor(q1, m); }
            int ig = ip * 4 + w;
            if (s == 0) pp[b * 32 + ig] = q0;
            float old = xsh[16 + 32 * w + s];
            float val = (s == 31) ? 1.0f - (1.0f - old) * q1 : old;  // 1-(1-old)*(1-urule)
            out[b * OUTSTRIDE + 16 + ig * 32 + s] = val;
        }
    }
}

// Finalize: nullary probsum across all i per batch + nullary output (16 channels).
__global__ __launch_bounds__(1024) void dnf_final(
    const float* __restrict__ nullary, const float* __restrict__ pp,
    float* __restrict__ out)
{
    int t = threadIdx.x;
    int b = t >> 5, s = t & 31;
    float v = pp[b * 32 + s];
#pragma unroll
    for (int m = 1; m < 32; m <<= 1) v *= __shfl_xor(v, m);
    if (s < 16) {
        float old = nullary[b * 16 + s];
        // merged = 1 - (1-old)*(1-rule0), rule0 = 1 - v  =>  1 - (1-old)*v
        float val = (s == 15) ? 1.0f - (1.0f - old) * v : old;
        out[b * OUTSTRIDE + s] = val;
    }
}

extern "C" void kernel_launch(void* const* d_in, const int* in_sizes, int n_in,
                              void* d_out, int out_size, void* d_ws, size_t ws_size,
                              hipStream_t stream) {
    const float* nullary = (const float*)d_in[0];
    const float* unary   = (const float*)d_in[1];
    const float* binary  = (const float*)d_in[2];
    const float* andk    = (const float*)d_in[3];
    const float* ork     = (const float*)d_in[4];
    float* out = (float*)d_out;
    float* pp  = (float*)d_ws;   // 1024 floats of scratch

    dnf_main<<<dim3(256), dim3(512), 0, stream>>>(nullary, unary, binary, andk, ork, out, pp);
    dnf_final<<<dim3(1), dim3(1024), 0, stream>>>(nullary, pp, out);
}